// Round 2
// baseline (197.558 us; speedup 1.0000x reference)
//
#include <hip/hip_runtime.h>
#include <cstddef>

// BoardModel: B=16384. out = [xf(32), a_mean(32), b2(32)] per sample, then board (3,22,12).
// MHA is degenerate (kv len 1 -> softmax==1): a_mean = out_proj(in_proj[64:96] @ b2 + b).
//
// R10 = R9 + register-budget / latency-batching fix:
//   - VGPR_Count was 40: the scheduler could not hoist LDS/SMEM loads, exposing
//     ~120cy ds_read latency per small batch at only ~4.5 resident waves/SIMD.
//     __launch_bounds__(256,4) caps at 4 blocks/CU (VGPR<=128) -- measured
//     residency was ~4.5 blocks anyway, so ceiling loss is ~0 and ILP gain is real.
//   - conv1: stage the full 6x6 input window (18 ds_read_b64) BEFORE the 600 FMAs.
//   - conv2: stage a contiguous 29-float window per ic before its 100 FMAs
//     (covers all 25 taps; contiguous -> mergeable reads, one lgkm batch).
//   - pcs piece entries hoisted to registers before the dense conv (hidden under FMAs).
//   - All R9 features kept: LDS-only barriers (no vmcnt drain), ballot piece pick,
//     bitmask board channels, transposed w1L, int2 content loads.

#define BATCH 16384
#define SPB   4
#define NBLK  (BATCH / SPB)
#define RS    18
#define SBE_SZ 432          // 24 rows x 18
#define P1OFF  432          // P1: [o*61 + p], p<60 -> 366 floats (bm overlays this in Phase A)
#define PCSOFF 800          // 16 ints
#define SS2    816          // floats per sample; 816*4 % 16 == 0
                            // tail overlays SBE: C2 192 @0, P2 48 @192, C3 64 @240,
                            // B2 32 @304, V 32 @336.

// LDS-only block barrier: do NOT drain vmcnt (global stores keep flowing).
#define BSYNC() asm volatile("s_waitcnt lgkmcnt(0)\ns_barrier" ::: "memory")

// ---- C_border precompute: cb[p*6+o] = sum over window taps hitting border-one cells,
//      summed over all 3 input channels (border is 1.0 in every channel). ----
__global__ __launch_bounds__(256)
void cborder_kernel(const float* __restrict__ w1, float* __restrict__ cb)
{
  int i = blockIdx.x * 256 + threadIdx.x;
  if (i >= 1584) return;
  int p = i / 6, o = i - p * 6;
  int y0 = p / 12, x0 = p - y0 * 12;
  float acc = 0.f;
#pragma unroll
  for (int dy = 0; dy < 5; ++dy)
#pragma unroll
    for (int dx = 0; dx < 5; ++dx) {
      int pr = y0 + dy - 2, pc = x0 + dx - 2;
      if (pr >= 0 && pr < 22 && pc >= 0 && pc < 12 &&
          (pr == 21 || pc == 0 || pc == 11)) {
        int k = dy * 5 + dx;
        acc += w1[(o * 3 + 0) * 25 + k] + w1[(o * 3 + 1) * 25 + k]
             + w1[(o * 3 + 2) * 25 + k];
      }
    }
  cb[p * 6 + o] = acc;
}

__global__ __launch_bounds__(256, 4)
void board_model_kernel(const int* __restrict__ t,           // (B,232)
                        const int* __restrict__ piece_table, // (8,4,4,4)
                        const float* __restrict__ w1, const float* __restrict__ b1,
                        const float* __restrict__ w2, const float* __restrict__ b2w,
                        const float* __restrict__ w3, const float* __restrict__ b3,
                        const float* __restrict__ wf1, const float* __restrict__ bf1,
                        const float* __restrict__ fcw, const float* __restrict__ fcb,
                        const float* __restrict__ ipw, const float* __restrict__ ipb,
                        const float* __restrict__ opw, const float* __restrict__ opb,
                        const float* __restrict__ cbg,        // (264,6) border contrib
                        float* __restrict__ out,              // (B,96)
                        float* __restrict__ out_board)        // (B,3,22,12)
{
  __shared__ __align__(16) float scr[SPB * SS2];
  __shared__ float w1L[300];     // ch1/ch2 taps, transposed: [(chm*25 + tap)*6 + o]
  __shared__ float cbL[1440];    // conv cells rows 0..19 only (cb[p*6+o], p<240)

  const int tid  = threadIdx.x;
  const int lane = tid & 63;
  const int wv   = tid >> 6;          // wave id == sample slot
  const int bb   = blockIdx.x * SPB;

  for (int i = tid; i < 300; i += 256) {
    int o = i % 6, tt = i / 6, m = tt / 25, tp = tt - m * 25;
    w1L[i] = w1[(o * 3 + m + 1) * 25 + tp];
  }
  for (int i = tid; i < 1440; i += 256) cbL[i] = cbg[i];

  // ---------------- Phase A: per-wave board build + board output ----------------
  {
    float* W = &scr[wv * SS2];
    int*   pcs = (int*)&scr[wv * SS2 + PCSOFF];
    int*   bmi = (int*)&scr[wv * SS2 + P1OFF];   // 44 ints: piece row bitmasks (Phase A only)
    const int* tr = t + (size_t)(bb + wv) * 232;

    float4* W4 = (float4*)W;
    for (int i = lane; i < 108; i += 64) W4[i] = float4{0.f, 0.f, 0.f, 0.f};
    if (lane < 44) bmi[lane] = 0;

    // content only (border handled via C_border): (r, b+1) -> SBE row r+2, col b+5
    // 210 ints at tr+22 (8B aligned); even pair offsets never cross a 10-wide row.
    {
      const int2* cp = (const int2*)(tr + 22);
      for (int v = lane; v < 105; v += 64) {
        int2 cv = cp[v];
        int i0 = v * 2;
        int r = i0 / 10, b = i0 - r * 10;
        W[(r + 2) * RS + b + 5] = (float)cv.x;
        W[(r + 2) * RS + b + 6] = (float)cv.y;
      }
    }

    // piece cells -> entry list (8 entries: e<4 ch1 uses y, e>=4 ch2 uses ny)
    // Every selected piece (t[:,8] in [0,7)) has exactly 4 set cells -> ballot+ctz.
    {
      const int* pt = piece_table + (tr[8] * 4 + tr[4]) * 16;
      int ptv = (lane < 16) ? pt[lane] : 0;
      unsigned long long bal = __ballot(ptv != 0);
      if (lane < 4) {
        unsigned x = (unsigned)bal & 0xffffu;
        for (int k = 0; k < lane; ++k) x &= x - 1;   // clear `lane` lowest set bits
        int sel = __builtin_ctz(x);
        int cy = sel >> 2, cx = sel & 3;
        int xx = cx + tr[1] - 2;
        int y  = cy + tr[2];
        int ny = y + tr[3];
        bool mask = (y >= 0) && (ny >= 0);
        bool xok  = (xx >= 0) && (xx < 10);
        bool v1 = mask && xok && (y < 21);
        bool v2 = mask && xok && (ny < 21);
        pcs[2 * lane + 0]       = v1 ? y  : -100;   // padded-board row
        pcs[2 * lane + 1]       = xx + 1;           // padded-board col
        pcs[2 * (lane + 4)]     = v2 ? ny : -100;
        pcs[2 * (lane + 4) + 1] = xx + 1;
        if (v1) atomicOr(&bmi[y],       1 << (xx + 1));
        if (v2) atomicOr(&bmi[22 + ny], 1 << (xx + 1));
      }
    }
    __builtin_amdgcn_wave_barrier();

    // board output: ch0 = border|content from SBE; ch1/2 = border | row bitmask
    float* ob = out_board + (size_t)(bb + wv) * 792;
    for (int v = lane; v < 198; v += 64) {
      int ch = v / 66, w = v - ch * 66;      // 66 float4 per channel
      int r = w / 3, c = (w - r * 3) * 4;    // c in {0,4,8}
      float val[4];
      if (ch == 0) {
#pragma unroll
        for (int d = 0; d < 4; ++d) {
          int cd = c + d;
          val[d] = (r == 21 || cd == 0 || cd == 11) ? 1.f
                 : W[(r + 2) * RS + cd + 4];
        }
      } else {
        int bits = bmi[(ch - 1) * 22 + r];
#pragma unroll
        for (int d = 0; d < 4; ++d) {
          int cd = c + d;
          val[d] = (r == 21 || cd == 0 || cd == 11 || ((bits >> cd) & 1)) ? 1.f : 0.f;
        }
      }
      *(float4*)(ob + v * 4) = float4{val[0], val[1], val[2], val[3]};
    }
  }
  BSYNC();   // guards w1L/cbL readiness (LDS only; board stores keep draining)

  // ------- Phase B: fused conv1+relu+pool1; wave = sample, lane = position <60 -------
  if (lane < 60) {
    int p = lane;
    int r = p / 6, c = p - r * 6;
    const float* Wq  = &scr[wv * SS2];
    const int*   pcs = (const int*)&scr[wv * SS2 + PCSOFF];

    // hoist piece entries into registers (LDS reads hide under the dense FMAs)
    int prA[8], pcA[8];
#pragma unroll
    for (int e = 0; e < 8; ++e) { prA[e] = pcs[2 * e]; pcA[e] = pcs[2 * e + 1]; }

    // stage the full 6x6 input window (18 x ds_read_b64, one lgkm batch)
    float rw[6][6];
    {
      const float* base = Wq + (2 * r) * RS + (2 * c + 2);
#pragma unroll
      for (int u = 0; u < 6; ++u) {
        float2 a0 = *(const float2*)(base + u * RS);
        float2 a1 = *(const float2*)(base + u * RS + 2);
        float2 a2 = *(const float2*)(base + u * RS + 4);
        rw[u][0] = a0.x; rw[u][1] = a0.y; rw[u][2] = a1.x;
        rw[u][3] = a1.y; rw[u][4] = a2.x; rw[u][5] = a2.y;
      }
    }

    float acc[2][2][6];
#pragma unroll
    for (int i = 0; i < 2; ++i)
#pragma unroll
      for (int j = 0; j < 2; ++j) {
        int pcell = (2 * r + i) * 12 + (2 * c + j);
#pragma unroll
        for (int o = 0; o < 6; ++o)
          acc[i][j][o] = b1[o] + cbL[pcell * 6 + o];
      }

    // dense ch0 (600 FMA); weights via GLOBAL uniform index -> SGPR
#pragma unroll
    for (int u = 0; u < 6; ++u) {
#pragma unroll
      for (int i = 0; i < 2; ++i) {
        if (u - i < 0 || u - i > 4) continue;   // folds at compile time
        const int ky = u - i;
#pragma unroll
        for (int j = 0; j < 2; ++j)
#pragma unroll
          for (int kx = 0; kx < 5; ++kx) {
            float xv = rw[u][j + kx];
#pragma unroll
            for (int o = 0; o < 6; ++o)
              acc[i][j][o] += xv * w1[o * 75 + ky * 5 + kx];   // uniform -> SGPR
          }
      }
    }

    // sparse piece taps (value==1 -> add weight); divergent -> w1L (o-contiguous)
#pragma unroll
    for (int e = 0; e < 8; ++e) {
      int pr = prA[e];
      if (pr < 0) continue;
      int pc = pcA[e];
      int chm = e >> 2;                       // 0 -> ch1, 1 -> ch2
      int dyb = pr + 2 - 2 * r;
      int dxb = pc + 2 - 2 * c;
      if (dyb < 0 || dyb > 5 || dxb < 0 || dxb > 5) continue;
#pragma unroll
      for (int i = 0; i < 2; ++i) {
        int dy = dyb - i;
        if ((unsigned)dy >= 5u) continue;
#pragma unroll
        for (int j = 0; j < 2; ++j) {
          int dx = dxb - j;
          if ((unsigned)dx >= 5u) continue;
          const float* wp = &w1L[(chm * 25 + dy * 5 + dx) * 6];
#pragma unroll
          for (int o = 0; o < 6; ++o)
            acc[i][j][o] += wp[o];
        }
      }
    }

    float* P1q = &scr[wv * SS2 + P1OFF];
#pragma unroll
    for (int o = 0; o < 6; ++o) {
      float v = fmaxf(acc[0][0][o], 0.f) + fmaxf(acc[0][1][o], 0.f)
              + fmaxf(acc[1][0][o], 0.f) + fmaxf(acc[1][1][o], 0.f);
      P1q[o * 61 + p] = 0.25f * v;
    }
  }
  BSYNC();   // P1 ready across waves (LDS only)

  // ---------------- conv2+relu: wave wvu -> out-channels [4wvu,4wvu+4), all samples ----
  const int wvu = __builtin_amdgcn_readfirstlane(wv);

  if (lane < 48) {
    int q = lane / 12, p = lane - q * 12;
    int r = p >> 1, c = p & 1;
    const float* P1q = &scr[q * SS2 + P1OFF];
    float a4[4];
#pragma unroll
    for (int oo = 0; oo < 4; ++oo) a4[oo] = b2w[4 * wvu + oo];
#pragma unroll
    for (int ic = 0; ic < 6; ++ic) {
      // stage a contiguous 29-float window: covers taps kr*6+kc (kr,kc<5)
      float vals[29];
      const float* pb = P1q + ic * 61 + r * 6 + c;
#pragma unroll
      for (int m = 0; m < 29; ++m) vals[m] = pb[m];
#pragma unroll
      for (int kr = 0; kr < 5; ++kr)
#pragma unroll
        for (int kc = 0; kc < 5; ++kc) {
          float xv = vals[kr * 6 + kc];
#pragma unroll
          for (int oo = 0; oo < 4; ++oo)
            a4[oo] += xv * w2[(((4 * wvu + oo) * 6 + ic) * 5 + kr) * 5 + kc];
        }
    }
    float* C2q = &scr[q * SS2];
#pragma unroll
    for (int oo = 0; oo < 4; ++oo)
      C2q[(4 * wvu + oo) * 12 + p] = fmaxf(a4[oo], 0.f);
  }
  BSYNC();   // C2 ready (LDS only)

  // ---------------- per-wave tail: wave q owns sample q ----------------
  {
    const int q = wvu;
    float* S = &scr[q * SS2];

    if (lane < 48) {
      int o = lane / 3, pr = lane - o * 3;
      float v = 0.25f * (S[o * 12 + 4 * pr] + S[o * 12 + 4 * pr + 1]
                       + S[o * 12 + 4 * pr + 2] + S[o * 12 + 4 * pr + 3]);
      S[192 + lane] = v;
    }
    __builtin_amdgcn_wave_barrier();

    {
      int o = lane;
      float acc = b3[o];
#pragma unroll
      for (int k = 0; k < 48; ++k) acc += S[192 + k] * w3[o * 48 + k];
      S[240 + o] = fmaxf(acc, 0.f);
    }
    __builtin_amdgcn_wave_barrier();

    {
      int j = lane & 31, h = lane >> 5;
      float part = 0.f;
#pragma unroll
      for (int kk = 0; kk < 32; ++kk) {
        int k = 32 * h + kk;
        part += S[240 + k] * wf1[j * 64 + k];
      }
      part += __shfl_xor(part, 32, 64);
      if (h == 0) {
        float acc = fmaxf(bf1[j] + part, 0.f);
        S[304 + j] = acc;
        out[(size_t)(bb + q) * 96 + 64 + j] = acc;
      }
    }
    __builtin_amdgcn_wave_barrier();

    {
      int j = lane & 31;
      if (lane < 32) {
        float acc = ipb[64 + j];
#pragma unroll
        for (int k = 0; k < 32; ++k) acc += S[304 + k] * ipw[(64 + j) * 32 + k];
        S[336 + j] = acc;
      } else {
        const int* tr = t + (size_t)(bb + q) * 232;
        float acc = fcb[j];
#pragma unroll
        for (int k = 0; k < 8; ++k) acc += (float)tr[k] * fcw[j * 8 + k];
        out[(size_t)(bb + q) * 96 + j] = fmaxf(acc, 0.f);
      }
    }
    __builtin_amdgcn_wave_barrier();

    if (lane < 32) {
      int j = lane;
      float acc = opb[j];
#pragma unroll
      for (int k = 0; k < 32; ++k) acc += S[336 + k] * opw[j * 32 + k];
      out[(size_t)(bb + q) * 96 + 32 + j] = acc;
    }
  }
}

extern "C" void kernel_launch(void* const* d_in, const int* in_sizes, int n_in,
                              void* d_out, int out_size, void* d_ws, size_t ws_size,
                              hipStream_t stream) {
  const int*   t   = (const int*)d_in[0];
  const int*   pt  = (const int*)d_in[1];
  const float* w1  = (const float*)d_in[2];
  const float* b1  = (const float*)d_in[3];
  const float* w2  = (const float*)d_in[4];
  const float* b2w = (const float*)d_in[5];
  const float* w3  = (const float*)d_in[6];
  const float* b3  = (const float*)d_in[7];
  const float* wf1 = (const float*)d_in[8];
  const float* bf1 = (const float*)d_in[9];
  const float* fcw = (const float*)d_in[10];
  const float* fcb = (const float*)d_in[11];
  // d_in[12] = emb : dead (softmax over singleton axis == 1)
  const float* ipw = (const float*)d_in[13];
  const float* ipb = (const float*)d_in[14];
  const float* opw = (const float*)d_in[15];
  const float* opb = (const float*)d_in[16];

  float* out       = (float*)d_out;
  float* out_board = out + (size_t)BATCH * 96;
  float* cbg       = (float*)d_ws;     // 1584 floats

  hipLaunchKernelGGL(cborder_kernel, dim3(7), dim3(256), 0, stream, w1, cbg);
  hipLaunchKernelGGL(board_model_kernel, dim3(NBLK), dim3(256), 0, stream,
                     t, pt, w1, b1, w2, b2w, w3, b3, wf1, bf1, fcw, fcb,
                     ipw, ipb, opw, opb, cbg, out, out_board);
}

// Round 3
// 193.780 us; speedup vs baseline: 1.0195x; 1.0195x over previous
//
#include <hip/hip_runtime.h>
#include <cstddef>

// BoardModel: B=16384. out = [xf(32), a_mean(32), b2(32)] per sample, then board (3,22,12).
// MHA is degenerate (kv len 1 -> softmax==1): a_mean = out_proj(in_proj[64:96] @ b2 + b).
//
// R11 = R10 + tail float4 weight access (the gather fix):
//   - Tail dot-products walked weight ROWS with per-k scalar loads: each wave-inst
//     gathered 64 distinct cachelines (row stride >= 64B). ~6k cacheline txns/wave
//     of L1 traffic -> the hidden 43% VALU-idle. All tail weight rows are 16B
//     aligned: load as float4 -> 4x fewer requests + cachelines, ~350 fewer addr ops.
//   - S[] operands read as b128 broadcasts (sample slab offsets 192/240/304/336 all
//     16B aligned). pool2 reads its 4 inputs as one b128.
//   - fc path: t[0..8) as two int4 (row stride 928B, 16B aligned).
//   - Everything else from R9/R10 kept: LDS-only barriers, ballot piece pick,
//     bitmask board channels, transposed w1L, int2 content loads, conv staging.

#define BATCH 16384
#define SPB   4
#define NBLK  (BATCH / SPB)
#define RS    18
#define SBE_SZ 432          // 24 rows x 18
#define P1OFF  432          // P1: [o*61 + p], p<60 -> 366 floats (bm overlays this in Phase A)
#define PCSOFF 800          // 16 ints
#define SS2    816          // floats per sample; 816*4 % 16 == 0
                            // tail overlays SBE: C2 192 @0, P2 48 @192, C3 64 @240,
                            // B2 32 @304, V 32 @336.

// LDS-only block barrier: do NOT drain vmcnt (global stores keep flowing).
#define BSYNC() asm volatile("s_waitcnt lgkmcnt(0)\ns_barrier" ::: "memory")

static __device__ __forceinline__ float dot4(float4 a, float4 b) {
  return a.x * b.x + a.y * b.y + a.z * b.z + a.w * b.w;
}

// ---- C_border precompute: cb[p*6+o] = sum over window taps hitting border-one cells,
//      summed over all 3 input channels (border is 1.0 in every channel). ----
__global__ __launch_bounds__(256)
void cborder_kernel(const float* __restrict__ w1, float* __restrict__ cb)
{
  int i = blockIdx.x * 256 + threadIdx.x;
  if (i >= 1584) return;
  int p = i / 6, o = i - p * 6;
  int y0 = p / 12, x0 = p - y0 * 12;
  float acc = 0.f;
#pragma unroll
  for (int dy = 0; dy < 5; ++dy)
#pragma unroll
    for (int dx = 0; dx < 5; ++dx) {
      int pr = y0 + dy - 2, pc = x0 + dx - 2;
      if (pr >= 0 && pr < 22 && pc >= 0 && pc < 12 &&
          (pr == 21 || pc == 0 || pc == 11)) {
        int k = dy * 5 + dx;
        acc += w1[(o * 3 + 0) * 25 + k] + w1[(o * 3 + 1) * 25 + k]
             + w1[(o * 3 + 2) * 25 + k];
      }
    }
  cb[p * 6 + o] = acc;
}

__global__ __launch_bounds__(256, 4)
void board_model_kernel(const int* __restrict__ t,           // (B,232)
                        const int* __restrict__ piece_table, // (8,4,4,4)
                        const float* __restrict__ w1, const float* __restrict__ b1,
                        const float* __restrict__ w2, const float* __restrict__ b2w,
                        const float* __restrict__ w3, const float* __restrict__ b3,
                        const float* __restrict__ wf1, const float* __restrict__ bf1,
                        const float* __restrict__ fcw, const float* __restrict__ fcb,
                        const float* __restrict__ ipw, const float* __restrict__ ipb,
                        const float* __restrict__ opw, const float* __restrict__ opb,
                        const float* __restrict__ cbg,        // (264,6) border contrib
                        float* __restrict__ out,              // (B,96)
                        float* __restrict__ out_board)        // (B,3,22,12)
{
  __shared__ __align__(16) float scr[SPB * SS2];
  __shared__ float w1L[300];     // ch1/ch2 taps, transposed: [(chm*25 + tap)*6 + o]
  __shared__ float cbL[1440];    // conv cells rows 0..19 only (cb[p*6+o], p<240)

  const int tid  = threadIdx.x;
  const int lane = tid & 63;
  const int wv   = tid >> 6;          // wave id == sample slot
  const int bb   = blockIdx.x * SPB;

  for (int i = tid; i < 300; i += 256) {
    int o = i % 6, tt = i / 6, m = tt / 25, tp = tt - m * 25;
    w1L[i] = w1[(o * 3 + m + 1) * 25 + tp];
  }
  for (int i = tid; i < 1440; i += 256) cbL[i] = cbg[i];

  // ---------------- Phase A: per-wave board build + board output ----------------
  {
    float* W = &scr[wv * SS2];
    int*   pcs = (int*)&scr[wv * SS2 + PCSOFF];
    int*   bmi = (int*)&scr[wv * SS2 + P1OFF];   // 44 ints: piece row bitmasks (Phase A only)
    const int* tr = t + (size_t)(bb + wv) * 232;

    float4* W4 = (float4*)W;
    for (int i = lane; i < 108; i += 64) W4[i] = float4{0.f, 0.f, 0.f, 0.f};
    if (lane < 44) bmi[lane] = 0;

    // content only (border handled via C_border): (r, b+1) -> SBE row r+2, col b+5
    // 210 ints at tr+22 (8B aligned); even pair offsets never cross a 10-wide row.
    {
      const int2* cp = (const int2*)(tr + 22);
      for (int v = lane; v < 105; v += 64) {
        int2 cv = cp[v];
        int i0 = v * 2;
        int r = i0 / 10, b = i0 - r * 10;
        W[(r + 2) * RS + b + 5] = (float)cv.x;
        W[(r + 2) * RS + b + 6] = (float)cv.y;
      }
    }

    // piece cells -> entry list (8 entries: e<4 ch1 uses y, e>=4 ch2 uses ny)
    // Every selected piece (t[:,8] in [0,7)) has exactly 4 set cells -> ballot+ctz.
    {
      const int* pt = piece_table + (tr[8] * 4 + tr[4]) * 16;
      int ptv = (lane < 16) ? pt[lane] : 0;
      unsigned long long bal = __ballot(ptv != 0);
      if (lane < 4) {
        unsigned x = (unsigned)bal & 0xffffu;
        for (int k = 0; k < lane; ++k) x &= x - 1;   // clear `lane` lowest set bits
        int sel = __builtin_ctz(x);
        int cy = sel >> 2, cx = sel & 3;
        int xx = cx + tr[1] - 2;
        int y  = cy + tr[2];
        int ny = y + tr[3];
        bool mask = (y >= 0) && (ny >= 0);
        bool xok  = (xx >= 0) && (xx < 10);
        bool v1 = mask && xok && (y < 21);
        bool v2 = mask && xok && (ny < 21);
        pcs[2 * lane + 0]       = v1 ? y  : -100;   // padded-board row
        pcs[2 * lane + 1]       = xx + 1;           // padded-board col
        pcs[2 * (lane + 4)]     = v2 ? ny : -100;
        pcs[2 * (lane + 4) + 1] = xx + 1;
        if (v1) atomicOr(&bmi[y],       1 << (xx + 1));
        if (v2) atomicOr(&bmi[22 + ny], 1 << (xx + 1));
      }
    }
    __builtin_amdgcn_wave_barrier();

    // board output: ch0 = border|content from SBE; ch1/2 = border | row bitmask
    float* ob = out_board + (size_t)(bb + wv) * 792;
    for (int v = lane; v < 198; v += 64) {
      int ch = v / 66, w = v - ch * 66;      // 66 float4 per channel
      int r = w / 3, c = (w - r * 3) * 4;    // c in {0,4,8}
      float val[4];
      if (ch == 0) {
#pragma unroll
        for (int d = 0; d < 4; ++d) {
          int cd = c + d;
          val[d] = (r == 21 || cd == 0 || cd == 11) ? 1.f
                 : W[(r + 2) * RS + cd + 4];
        }
      } else {
        int bits = bmi[(ch - 1) * 22 + r];
#pragma unroll
        for (int d = 0; d < 4; ++d) {
          int cd = c + d;
          val[d] = (r == 21 || cd == 0 || cd == 11 || ((bits >> cd) & 1)) ? 1.f : 0.f;
        }
      }
      *(float4*)(ob + v * 4) = float4{val[0], val[1], val[2], val[3]};
    }
  }
  BSYNC();   // guards w1L/cbL readiness (LDS only; board stores keep draining)

  // ------- Phase B: fused conv1+relu+pool1; wave = sample, lane = position <60 -------
  if (lane < 60) {
    int p = lane;
    int r = p / 6, c = p - r * 6;
    const float* Wq  = &scr[wv * SS2];
    const int*   pcs = (const int*)&scr[wv * SS2 + PCSOFF];

    // hoist piece entries into registers (LDS reads hide under the dense FMAs)
    int prA[8], pcA[8];
#pragma unroll
    for (int e = 0; e < 8; ++e) { prA[e] = pcs[2 * e]; pcA[e] = pcs[2 * e + 1]; }

    // stage the full 6x6 input window (18 x ds_read_b64, one lgkm batch)
    float rw[6][6];
    {
      const float* base = Wq + (2 * r) * RS + (2 * c + 2);
#pragma unroll
      for (int u = 0; u < 6; ++u) {
        float2 a0 = *(const float2*)(base + u * RS);
        float2 a1 = *(const float2*)(base + u * RS + 2);
        float2 a2 = *(const float2*)(base + u * RS + 4);
        rw[u][0] = a0.x; rw[u][1] = a0.y; rw[u][2] = a1.x;
        rw[u][3] = a1.y; rw[u][4] = a2.x; rw[u][5] = a2.y;
      }
    }

    float acc[2][2][6];
#pragma unroll
    for (int i = 0; i < 2; ++i)
#pragma unroll
      for (int j = 0; j < 2; ++j) {
        int pcell = (2 * r + i) * 12 + (2 * c + j);
#pragma unroll
        for (int o = 0; o < 6; ++o)
          acc[i][j][o] = b1[o] + cbL[pcell * 6 + o];
      }

    // dense ch0 (600 FMA); weights via GLOBAL uniform index -> SGPR
#pragma unroll
    for (int u = 0; u < 6; ++u) {
#pragma unroll
      for (int i = 0; i < 2; ++i) {
        if (u - i < 0 || u - i > 4) continue;   // folds at compile time
        const int ky = u - i;
#pragma unroll
        for (int j = 0; j < 2; ++j)
#pragma unroll
          for (int kx = 0; kx < 5; ++kx) {
            float xv = rw[u][j + kx];
#pragma unroll
            for (int o = 0; o < 6; ++o)
              acc[i][j][o] += xv * w1[o * 75 + ky * 5 + kx];   // uniform -> SGPR
          }
      }
    }

    // sparse piece taps (value==1 -> add weight); divergent -> w1L (o-contiguous)
#pragma unroll
    for (int e = 0; e < 8; ++e) {
      int pr = prA[e];
      if (pr < 0) continue;
      int pc = pcA[e];
      int chm = e >> 2;                       // 0 -> ch1, 1 -> ch2
      int dyb = pr + 2 - 2 * r;
      int dxb = pc + 2 - 2 * c;
      if (dyb < 0 || dyb > 5 || dxb < 0 || dxb > 5) continue;
#pragma unroll
      for (int i = 0; i < 2; ++i) {
        int dy = dyb - i;
        if ((unsigned)dy >= 5u) continue;
#pragma unroll
        for (int j = 0; j < 2; ++j) {
          int dx = dxb - j;
          if ((unsigned)dx >= 5u) continue;
          const float* wp = &w1L[(chm * 25 + dy * 5 + dx) * 6];
#pragma unroll
          for (int o = 0; o < 6; ++o)
            acc[i][j][o] += wp[o];
        }
      }
    }

    float* P1q = &scr[wv * SS2 + P1OFF];
#pragma unroll
    for (int o = 0; o < 6; ++o) {
      float v = fmaxf(acc[0][0][o], 0.f) + fmaxf(acc[0][1][o], 0.f)
              + fmaxf(acc[1][0][o], 0.f) + fmaxf(acc[1][1][o], 0.f);
      P1q[o * 61 + p] = 0.25f * v;
    }
  }
  BSYNC();   // P1 ready across waves (LDS only)

  // ---------------- conv2+relu: wave wvu -> out-channels [4wvu,4wvu+4), all samples ----
  const int wvu = __builtin_amdgcn_readfirstlane(wv);

  if (lane < 48) {
    int q = lane / 12, p = lane - q * 12;
    int r = p >> 1, c = p & 1;
    const float* P1q = &scr[q * SS2 + P1OFF];
    float a4[4];
#pragma unroll
    for (int oo = 0; oo < 4; ++oo) a4[oo] = b2w[4 * wvu + oo];
#pragma unroll
    for (int ic = 0; ic < 6; ++ic) {
      // stage a contiguous 29-float window: covers taps kr*6+kc (kr,kc<5)
      float vals[29];
      const float* pb = P1q + ic * 61 + r * 6 + c;
#pragma unroll
      for (int m = 0; m < 29; ++m) vals[m] = pb[m];
#pragma unroll
      for (int kr = 0; kr < 5; ++kr)
#pragma unroll
        for (int kc = 0; kc < 5; ++kc) {
          float xv = vals[kr * 6 + kc];
#pragma unroll
          for (int oo = 0; oo < 4; ++oo)
            a4[oo] += xv * w2[(((4 * wvu + oo) * 6 + ic) * 5 + kr) * 5 + kc];
        }
    }
    float* C2q = &scr[q * SS2];
#pragma unroll
    for (int oo = 0; oo < 4; ++oo)
      C2q[(4 * wvu + oo) * 12 + p] = fmaxf(a4[oo], 0.f);
  }
  BSYNC();   // C2 ready (LDS only)

  // ---------------- per-wave tail: wave q owns sample q ----------------
  {
    const int q = wvu;
    float* S = &scr[q * SS2];

    // pool2: one b128 per lane (o*12+4*pr is a multiple of 4 floats; slab 16B aligned)
    if (lane < 48) {
      int o = lane / 3, pr = lane - o * 3;
      float4 v4 = *(const float4*)(S + o * 12 + 4 * pr);
      S[192 + lane] = 0.25f * (v4.x + v4.y + v4.z + v4.w);
    }
    __builtin_amdgcn_wave_barrier();

    // conv3 (fc over 48): per-lane row of w3 as 12 float4 (row = 192B, 16B aligned)
    {
      int o = lane;
      const float4* w34 = (const float4*)(w3 + o * 48);
      const float4* S4  = (const float4*)(S + 192);
      float acc = b3[o];
#pragma unroll
      for (int m = 0; m < 12; ++m)
        acc += dot4(S4[m], w34[m]);
      S[240 + o] = fmaxf(acc, 0.f);
    }
    __builtin_amdgcn_wave_barrier();

    // lfc1: rows of wf1 (256B) as float4; split-k halves combined via shfl
    {
      int j = lane & 31, h = lane >> 5;
      const float4* wf4 = (const float4*)(wf1 + j * 64 + 32 * h);
      const float4* S4  = (const float4*)(S + 240 + 32 * h);
      float part = 0.f;
#pragma unroll
      for (int m = 0; m < 8; ++m)
        part += dot4(S4[m], wf4[m]);
      part += __shfl_xor(part, 32, 64);
      if (h == 0) {
        float acc = fmaxf(bf1[j] + part, 0.f);
        S[304 + j] = acc;
        out[(size_t)(bb + q) * 96 + 64 + j] = acc;
      }
    }
    __builtin_amdgcn_wave_barrier();

    {
      int j = lane & 31;
      if (lane < 32) {
        // v-proj: rows 64..95 of ipw (128B rows) as float4
        const float4* ip4 = (const float4*)(ipw + (size_t)(64 + j) * 32);
        const float4* S4  = (const float4*)(S + 304);
        float acc = ipb[64 + j];
#pragma unroll
        for (int m = 0; m < 8; ++m)
          acc += dot4(S4[m], ip4[m]);
        S[336 + j] = acc;
      } else {
        // xf: t row is 928B (16B aligned); fcw row is 32B
        const int4* t4 = (const int4*)(t + (size_t)(bb + q) * 232);
        int4 ta = t4[0], tb = t4[1];
        const float4* fc4 = (const float4*)(fcw + j * 8);
        float4 wa = fc4[0], wb = fc4[1];
        float acc = fcb[j]
                  + (float)ta.x * wa.x + (float)ta.y * wa.y
                  + (float)ta.z * wa.z + (float)ta.w * wa.w
                  + (float)tb.x * wb.x + (float)tb.y * wb.y
                  + (float)tb.z * wb.z + (float)tb.w * wb.w;
        out[(size_t)(bb + q) * 96 + j] = fmaxf(acc, 0.f);
      }
    }
    __builtin_amdgcn_wave_barrier();

    if (lane < 32) {
      int j = lane;
      const float4* op4 = (const float4*)(opw + j * 32);
      const float4* S4  = (const float4*)(S + 336);
      float acc = opb[j];
#pragma unroll
      for (int m = 0; m < 8; ++m)
        acc += dot4(S4[m], op4[m]);
      out[(size_t)(bb + q) * 96 + 32 + j] = acc;
    }
  }
}

extern "C" void kernel_launch(void* const* d_in, const int* in_sizes, int n_in,
                              void* d_out, int out_size, void* d_ws, size_t ws_size,
                              hipStream_t stream) {
  const int*   t   = (const int*)d_in[0];
  const int*   pt  = (const int*)d_in[1];
  const float* w1  = (const float*)d_in[2];
  const float* b1  = (const float*)d_in[3];
  const float* w2  = (const float*)d_in[4];
  const float* b2w = (const float*)d_in[5];
  const float* w3  = (const float*)d_in[6];
  const float* b3  = (const float*)d_in[7];
  const float* wf1 = (const float*)d_in[8];
  const float* bf1 = (const float*)d_in[9];
  const float* fcw = (const float*)d_in[10];
  const float* fcb = (const float*)d_in[11];
  // d_in[12] = emb : dead (softmax over singleton axis == 1)
  const float* ipw = (const float*)d_in[13];
  const float* ipb = (const float*)d_in[14];
  const float* opw = (const float*)d_in[15];
  const float* opb = (const float*)d_in[16];

  float* out       = (float*)d_out;
  float* out_board = out + (size_t)BATCH * 96;
  float* cbg       = (float*)d_ws;     // 1584 floats

  hipLaunchKernelGGL(cborder_kernel, dim3(7), dim3(256), 0, stream, w1, cbg);
  hipLaunchKernelGGL(board_model_kernel, dim3(NBLK), dim3(256), 0, stream,
                     t, pt, w1, b1, w2, b2w, w3, b3, wf1, bf1, fcw, fcb,
                     ipw, ipb, opw, opb, cbg, out, out_board);
}